// Round 12
// baseline (234.615 us; speedup 1.0000x reference)
//
#include <hip/hip_runtime.h>
#include <hip/hip_bf16.h>

typedef unsigned short u16;
typedef __attribute__((ext_vector_type(8))) short bf16x8;
typedef __attribute__((ext_vector_type(4))) short bf16x4;
typedef __attribute__((ext_vector_type(4))) float f32x4;

#define DD 1024
#define TT 2048
#define HH 16
#define BB 4
#define DK 64
#define MM 8192  // B*T

#define QSCALE 0.180336880f  // 0.125 * log2(e)

__device__ __forceinline__ u16 f2b(float x) {
  __hip_bfloat16 h = __float2bfloat16(x);
  return *reinterpret_cast<u16*>(&h);
}

// packed f32x2 -> bf16x2 (v_cvt_pk_bf16_f32)
__device__ __forceinline__ unsigned pk2(float a, float b) {
  float2 t; t.x = a; t.y = b;
  __hip_bfloat162 h = __float22bfloat162_rn(t);
  union { __hip_bfloat162 h; unsigned u; } cv;
  cv.h = h;
  return cv.u;
}

#define GLD16(gp, lp)                                                         \
  __builtin_amdgcn_global_load_lds(                                           \
      (const __attribute__((address_space(1))) unsigned int*)(gp),            \
      (__attribute__((address_space(3))) unsigned int*)(lp), 16, 0, 0)

// ---------------- prep: weight transpose+cast (blocks 0..4095) and
// x fp32->bf16 cast (blocks 4096..12287) in ONE dispatch ----------------
__global__ __launch_bounds__(256) void prep_kernel(
    const float* __restrict__ x, u16* __restrict__ xb,
    const float* __restrict__ W0, const float* __restrict__ W1,
    const float* __restrict__ W2, const float* __restrict__ W3,
    u16* __restrict__ O0, u16* __restrict__ O1,
    u16* __restrict__ O2, u16* __restrict__ O3) {
  __shared__ float tile[32][33];
  int bid = blockIdx.x;
  if (bid >= 4096) {  // cast part: 8192 blocks x 1024 elems
    int i = ((bid - 4096) * 256 + threadIdx.x) * 4;
    float4 v = *reinterpret_cast<const float4*>(x + i);
    ushort4 o;
    o.x = f2b(v.x); o.y = f2b(v.y); o.z = f2b(v.z); o.w = f2b(v.w);
    *reinterpret_cast<ushort4*>(xb + i) = o;
    return;
  }
  const float* W; u16* O;
  switch (bid >> 10) {
    case 0: W = W0; O = O0; break;
    case 1: W = W1; O = O1; break;
    case 2: W = W2; O = O2; break;
    default: W = W3; O = O3; break;
  }
  int tx = threadIdx.x & 31, ty = threadIdx.x >> 5;  // 32 x 8
  int bx = (bid & 31) * 32;
  int by = ((bid >> 5) & 31) * 32;
#pragma unroll
  for (int j = 0; j < 4; j++)
    tile[ty + j * 8][tx] = W[(size_t)(by + ty + j * 8) * DD + bx + tx];
  __syncthreads();
#pragma unroll
  for (int j = 0; j < 4; j++)
    O[(size_t)(bx + ty + j * 8) * DD + by + tx] = f2b(tile[tx][ty + j * 8]);
}

// ============ common 128x128 MFMA GEMM body, BK=64, XOR-swizzled LDS =======
#define GEMM_STAGE(Aptr, Bptr, Asl, Bsl)                                      \
  _Pragma("unroll") for (int c = 0; c < 4; c++) {                             \
    int idx = tid * 8 + c * 2048;                                             \
    int row = idx >> 6, ck = idx & 63;                                        \
    int src = ck ^ ((row & 7) << 3);                                          \
    GLD16(Aptr + (size_t)(m0 + row) * DD + k0 + src, Asl + idx);              \
    GLD16(Bptr + (size_t)(n0 + row) * DD + k0 + src, Bsl + idx);              \
  }

#define GEMM_MFMA(Asl, Bsl)                                                   \
  _Pragma("unroll") for (int half = 0; half < 2; half++) {                    \
    bf16x8 af[4], bfr[4];                                                     \
    _Pragma("unroll") for (int mb = 0; mb < 4; mb++) {                        \
      int r = wm + mb * 16 + l16;                                             \
      af[mb] = *reinterpret_cast<const bf16x8*>(                              \
          &Asl[r * 64 + ((half * 32 + quad * 8) ^ ((r & 7) << 3))]);          \
    }                                                                         \
    _Pragma("unroll") for (int nb = 0; nb < 4; nb++) {                        \
      int r = wn + nb * 16 + l16;                                             \
      bfr[nb] = *reinterpret_cast<const bf16x8*>(                             \
          &Bsl[r * 64 + ((half * 32 + quad * 8) ^ ((r & 7) << 3))]);          \
    }                                                                         \
    _Pragma("unroll") for (int mb = 0; mb < 4; mb++)                          \
      _Pragma("unroll") for (int nb = 0; nb < 4; nb++)                        \
          acc[mb][nb] = __builtin_amdgcn_mfma_f32_16x16x32_bf16(              \
              af[mb], bfr[nb], acc[mb][nb], 0, 0, 0);                         \
  }

// ---------------- fused QKV GEMM: grid (64, 8, 3) ----------------
__global__ __launch_bounds__(256, 4) void gemm_qkv_kernel(
    const u16* __restrict__ A,
    const u16* __restrict__ WtQ, const u16* __restrict__ WtK,
    const u16* __restrict__ WtV,
    const float* __restrict__ bq, const float* __restrict__ bk,
    const float* __restrict__ bv,
    u16* __restrict__ Qo, u16* __restrict__ Ko, u16* __restrict__ Vo) {
  __shared__ __align__(16) u16 smem[17408];  // 34816 B union
  u16* As = smem;          // [128][64] main loop
  u16* Bs = smem + 8192;   // [128][64] main loop
  u16* Vs = smem;          // [128][136] epilogue overlay (z==2 only)
  int z = blockIdx.z;
  const u16* Bt = (z == 0) ? WtQ : ((z == 1) ? WtK : WtV);
  const float* bias = (z == 0) ? bq : ((z == 1) ? bk : bv);
  int tid = threadIdx.x;
  int wave = tid >> 6, lane = tid & 63;
  int quad = lane >> 4, l16 = lane & 15;
  int m0 = blockIdx.x * 128, n0 = blockIdx.y * 128;
  int wm = (wave >> 1) * 64, wn = (wave & 1) * 64;

  f32x4 acc[4][4];
#pragma unroll
  for (int i = 0; i < 4; i++)
#pragma unroll
    for (int j = 0; j < 4; j++) acc[i][j] = (f32x4){0.f, 0.f, 0.f, 0.f};

  for (int k0 = 0; k0 < DD; k0 += 64) {
    GEMM_STAGE(A, Bt, As, Bs)
    __syncthreads();
    GEMM_MFMA(As, Bs)
    __syncthreads();
  }
  // final loop barrier done: As/Bs dead, Vs overlay is safe.

  if (z == 2) {  // V: transpose to (B,H,64,T) via LDS
#pragma unroll
    for (int mb = 0; mb < 4; mb++)
#pragma unroll
      for (int nb = 0; nb < 4; nb++) {
        int col = wn + nb * 16 + l16;
        float bv2 = bias[n0 + col];
#pragma unroll
        for (int r = 0; r < 4; r++) {
          int row = wm + mb * 16 + quad * 4 + r;
          Vs[col * 136 + row] = f2b(acc[mb][nb][r] + bv2);
        }
      }
    __syncthreads();
    int b = m0 >> 11;
    int tloc = m0 & 2047;
#pragma unroll
    for (int i = 0; i < 8; i++) {
      int idx = tid * 8 + i * 2048;
      int row = idx >> 7, col = idx & 127;
      uint4 v = *reinterpret_cast<const uint4*>(&Vs[row * 136 + col]);
      int ncol = n0 + row, h = ncol >> 6, dd = ncol & 63;
      *reinterpret_cast<uint4*>(
          Vo + (((size_t)(b * HH + h) * DK) + dd) * TT + tloc + col) = v;
    }
    return;
  }

  u16* outp = (z == 0) ? Qo : Ko;
  float scale = (z == 0) ? QSCALE : 1.0f;
#pragma unroll
  for (int mb = 0; mb < 4; mb++) {
#pragma unroll
    for (int nb = 0; nb < 4; nb++) {
      int col = n0 + wn + nb * 16 + l16;
      float bv2 = bias[col];
#pragma unroll
      for (int r = 0; r < 4; r++) {
        int row = m0 + wm + mb * 16 + quad * 4 + r;
        float val = (acc[mb][nb][r] + bv2) * scale;
        int hh = col >> 6, dd = col & 63;
        int b = row >> 11, t = row & 2047;
        outp[(((size_t)(b * HH + hh) * TT) + t) * DK + dd] = f2b(val);
      }
    }
  }
}

// ---------------- output-projection GEMM (ctx @ Wo + bo -> fp32) ----------
__global__ __launch_bounds__(256, 4) void gemm_out_kernel(
    const u16* __restrict__ A, const u16* __restrict__ Bt,
    const float* __restrict__ bias, float* __restrict__ outp) {
  __shared__ __align__(16) u16 As[128 * 64];
  __shared__ __align__(16) u16 Bs[128 * 64];
  int tid = threadIdx.x;
  int wave = tid >> 6, lane = tid & 63;
  int quad = lane >> 4, l16 = lane & 15;
  int m0 = blockIdx.x * 128, n0 = blockIdx.y * 128;
  int wm = (wave >> 1) * 64, wn = (wave & 1) * 64;

  f32x4 acc[4][4];
#pragma unroll
  for (int i = 0; i < 4; i++)
#pragma unroll
    for (int j = 0; j < 4; j++) acc[i][j] = (f32x4){0.f, 0.f, 0.f, 0.f};

  for (int k0 = 0; k0 < DD; k0 += 64) {
    GEMM_STAGE(A, Bt, As, Bs)
    __syncthreads();
    GEMM_MFMA(As, Bs)
    __syncthreads();
  }

#pragma unroll
  for (int mb = 0; mb < 4; mb++) {
#pragma unroll
    for (int nb = 0; nb < 4; nb++) {
      int col = n0 + wn + nb * 16 + l16;
      float bv = bias[col];
#pragma unroll
      for (int r = 0; r < 4; r++) {
        int row = m0 + wm + mb * 16 + quad * 4 + r;
        outp[(size_t)row * DD + col] = acc[mb][nb][r] + bv;
      }
    }
  }
}

// ---------------- flash attention: KVBLK=128, 32 q-rows/wave, DMA staging --
// Round-11 config (best) + FORCED ILP: round-11 counters showed MfmaUtil 37%
// at VGPR=88 — the compiler serialized the 16 independent (kb,s) chains
// (ds_read->QK->exp->pack->PV ~250cyc each ~= the measured 4500cyc/kt).
// Fix: split the kb loop into PHASE 1 (all 16 QK^T MFMAs -> sacc[8][2],
// compile-time indexed) and PHASE 2 (softmax+PV per chain). Phase 1 hands
// the scheduler 16 independent MFMA chains back-to-back; phase 2's PV MFMAs
// overlap the next chain's exp2 on the trans pipe. VGPR budget: sacc 64 +
// oacc 32 + qf 16 + lsum 8 + misc ~= 160-200 < 256 cap @ (256,2) — same
// 2 waves/SIMD occupancy step, no spill expected (round-8 lesson: watch
// WRITE_SIZE for scratch traffic).
// grid 512 (64 bh x 8 px), block 256 (4 waves). Wave owns 32 q-rows as TWO
// 16-row subblocks (s=0,1) sharing every K/V fragment read.
// Zero-register DMA staging via global_load_lds into unpadded swizzled LDS.
// T5 setprio around the compute cluster (round-11: +3%).
// Swizzles: K[2][128][64]: src col^((key&7)<<3), read (..)^((l16&7)<<3).
//   V[2][64][128]: 16B granule G=key>>3, src G^(d&7); read
//   vcol = ((kb*2+(quad>>1)) ^ (l16&7))<<3 | (quad&1)*4.
// Paired q-tiles qt=15-px then px: 17 kt per block, no straggler tail.
// Diagonal: wave-uniform skip kb>2*wave+1; subblock s skips kb>2*wave+s,
// masks quad*4+r>l16 at kb==2*wave+s.
__global__ __launch_bounds__(256, 2) void attn_kernel(
    const u16* __restrict__ Q, const u16* __restrict__ K,
    const u16* __restrict__ VT, u16* __restrict__ ctx) {
  __shared__ __align__(16) u16 Ks[2][128][64];   // [buf][key][d]
  __shared__ __align__(16) u16 Vt[2][64][128];   // [buf][d][key]

  int tid = threadIdx.x;
  int wave = tid >> 6, lane = tid & 63;
  int quad = lane >> 4, l16 = lane & 15;
  int bid = blockIdx.x;
  int bh = bid & 63;
  int px = bid >> 6;  // 0..7
  int b = bh >> 4, h = bh & 15;
  const u16* Qh = Q + (size_t)bh * TT * DK;
  const u16* Kh = K + (size_t)bh * TT * DK;
  const u16* Vh = VT + (size_t)bh * DK * TT;

  const bf16x4 ones = (bf16x4){0x3F80, 0x3F80, 0x3F80, 0x3F80};  // bf16 1.0
  int l8 = l16 & 7;            // hoisted swizzle masks
  int ksw = l8 << 3;

// stage K/V tile (ktile) into buffer bb via async DMA, zero registers
#define ATTN_STAGE(bb, ktile)                                                 \
  _Pragma("unroll") for (int c = 0; c < 4; c++) {                             \
    int idx = tid * 8 + c * 2048;                                             \
    int krow = idx >> 6, kcol = idx & 63;                                     \
    GLD16(Kh + (size_t)(ktile) * 8192 + krow * 64 +                           \
              (kcol ^ ((krow & 7) << 3)),                                     \
          &Ks[bb][0][0] + idx);                                               \
    int vd = idx >> 7, vg = (idx & 127) >> 3;                                 \
    GLD16(Vh + (size_t)vd * TT + (ktile) * 128 + ((vg ^ (vd & 7)) << 3),      \
          &Vt[bb][0][0] + idx);                                               \
  }

  for (int phase = 0; phase < 2; phase++) {
    int qtc = phase ? px : (15 - px);
    __syncthreads();  // prev-phase epilogue reused Ks[0] as Obuf

    bf16x8 qf[2][2];
#pragma unroll
    for (int s = 0; s < 2; s++) {
      const u16* qrow =
          Qh + (size_t)(qtc * 128 + wave * 32 + s * 16 + l16) * DK + quad * 8;
      qf[s][0] = *reinterpret_cast<const bf16x8*>(qrow);
      qf[s][1] = *reinterpret_cast<const bf16x8*>(qrow + 32);
    }

    ATTN_STAGE(0, 0)
    __syncthreads();  // drains vmcnt -> tile 0 ready

    f32x4 oacc[2][4];
    f32x4 lsum[2];
#pragma unroll
    for (int s = 0; s < 2; s++) {
      lsum[s] = (f32x4){0.f, 0.f, 0.f, 0.f};
#pragma unroll
      for (int dt = 0; dt < 4; dt++) oacc[s][dt] = (f32x4){0.f, 0.f, 0.f, 0.f};
    }

    for (int kt = 0; kt <= qtc; kt++) {
      int cur = kt & 1, nxt = cur ^ 1;
      bool more = kt < qtc;
      bool diag = kt == qtc;
      if (more) {
        ATTN_STAGE(nxt, kt + 1)  // async; lands before end-of-kt barrier
      }

      __builtin_amdgcn_s_setprio(1);  // favor compute over staging waves

      // ---- PHASE 1: all QK^T MFMAs (16 independent chains) ----
      f32x4 sacc[8][2];
#pragma unroll
      for (int kb = 0; kb < 8; kb++) {
        if (diag && kb > 2 * wave + 1) continue;  // wave-uniform skip
        int krow = kb * 16 + l16;
        bf16x8 kf0 =
            *reinterpret_cast<const bf16x8*>(&Ks[cur][krow][(quad * 8) ^ ksw]);
        bf16x8 kf1 = *reinterpret_cast<const bf16x8*>(
            &Ks[cur][krow][(32 + quad * 8) ^ ksw]);
#pragma unroll
        for (int s = 0; s < 2; s++) {
          if (diag && kb > 2 * wave + s) continue;  // subblock causal skip
          f32x4 t = (f32x4){0.f, 0.f, 0.f, 0.f};
          t = __builtin_amdgcn_mfma_f32_16x16x32_bf16(kf0, qf[s][0], t, 0, 0, 0);
          t = __builtin_amdgcn_mfma_f32_16x16x32_bf16(kf1, qf[s][1], t, 0, 0, 0);
          sacc[kb][s] = t;
        }
      }

      // ---- PHASE 2: mask + exp2 + pack + lsum/PV MFMAs ----
#pragma unroll
      for (int kb = 0; kb < 8; kb++) {
        if (diag && kb > 2 * wave + 1) continue;
        bf16x4 vf[4];
        int vcol = (((kb * 2 + (quad >> 1)) ^ l8) << 3) + (quad & 1) * 4;
#pragma unroll
        for (int dt = 0; dt < 4; dt++)
          vf[dt] =
              *reinterpret_cast<const bf16x4*>(&Vt[cur][dt * 16 + l16][vcol]);
#pragma unroll
        for (int s = 0; s < 2; s++) {
          if (diag && kb > 2 * wave + s) continue;
          f32x4 sv = sacc[kb][s];
          if (diag && kb == 2 * wave + s) {  // mask inside diagonal 16x16
#pragma unroll
            for (int r = 0; r < 4; r++)
              if (quad * 4 + r > l16) sv[r] = -__builtin_inff();
          }
          float p0 = __builtin_amdgcn_exp2f(sv[0]);
          float p1 = __builtin_amdgcn_exp2f(sv[1]);
          float p2 = __builtin_amdgcn_exp2f(sv[2]);
          float p3 = __builtin_amdgcn_exp2f(sv[3]);
          union { unsigned u[2]; bf16x4 v; } pk;
          pk.u[0] = pk2(p0, p1);
          pk.u[1] = pk2(p2, p3);
          lsum[s] = __builtin_amdgcn_mfma_f32_16x16x16bf16_1k(pk.v, ones, lsum[s], 0, 0, 0);
#pragma unroll
          for (int dt = 0; dt < 4; dt++)
            oacc[s][dt] = __builtin_amdgcn_mfma_f32_16x16x16bf16_1k(
                pk.v, vf[dt], oacc[s][dt], 0, 0, 0);
        }
      }
      __builtin_amdgcn_s_setprio(0);

      __syncthreads();  // single barrier per kt (drains DMA into nxt)
    }

    // lsum[s][r] = row-sum for q = quad*4 + r of subblock s -> invert
    f32x4 inv[2];
#pragma unroll
    for (int s = 0; s < 2; s++)
#pragma unroll
      for (int r = 0; r < 4; r++) inv[s][r] = 1.0f / lsum[s][r];

    // stage O through LDS (wave-private rows of flat Obuf over Ks[0])
    u16* Obuf = &Ks[0][0][0];  // 128 rows x stride 64
#pragma unroll
    for (int s = 0; s < 2; s++)
#pragma unroll
      for (int dt = 0; dt < 4; dt++)
#pragma unroll
        for (int r = 0; r < 4; r++)
          Obuf[(wave * 32 + s * 16 + quad * 4 + r) * 64 + dt * 16 + l16] =
              f2b(oacc[s][dt][r] * inv[s][r]);
    asm volatile("s_waitcnt lgkmcnt(0)" ::: "memory");
#pragma unroll
    for (int i = 0; i < 4; i++) {
      int idx = lane * 8 + i * 512;
      int row = idx >> 6, colc = idx & 63;  // row 0..31 local to wave
      uint4 v =
          *reinterpret_cast<const uint4*>(&Obuf[(wave * 32 + row) * 64 + colc]);
      int t = qtc * 128 + wave * 32 + row;
      *reinterpret_cast<uint4*>(
          ctx + ((size_t)(b * TT + t)) * DD + h * DK + colc) = v;
    }
  }
#undef ATTN_STAGE
}

// ---------------- launch ----------------
extern "C" void kernel_launch(void* const* d_in, const int* in_sizes, int n_in,
                              void* d_out, int out_size, void* d_ws, size_t ws_size,
                              hipStream_t stream) {
  const float* x  = (const float*)d_in[0];
  const float* Wq = (const float*)d_in[1];
  const float* bq = (const float*)d_in[2];
  const float* Wk = (const float*)d_in[3];
  const float* bk = (const float*)d_in[4];
  const float* Wv = (const float*)d_in[5];
  const float* bv = (const float*)d_in[6];
  const float* Wo = (const float*)d_in[7];
  const float* bo = (const float*)d_in[8];
  float* out = (float*)d_out;

  char* ws = (char*)d_ws;
  size_t off = 0;
  u16* xb  = (u16*)(ws + off); off += (size_t)MM * DD * 2;
  u16* wtq = (u16*)(ws + off); off += (size_t)DD * DD * 2;
  u16* wtk = (u16*)(ws + off); off += (size_t)DD * DD * 2;
  u16* wtv = (u16*)(ws + off); off += (size_t)DD * DD * 2;
  u16* wto = (u16*)(ws + off); off += (size_t)DD * DD * 2;
  u16* Qb  = (u16*)(ws + off); off += (size_t)MM * DD * 2;
  u16* Kb  = (u16*)(ws + off); off += (size_t)MM * DD * 2;
  u16* VTb = (u16*)(ws + off); off += (size_t)MM * DD * 2;
  u16* ctx = (u16*)(ws + off); off += (size_t)MM * DD * 2;

  {
    // 4096 transpose blocks + 8192 cast blocks, one dispatch
    prep_kernel<<<12288, 256, 0, stream>>>(x, xb, Wq, Wk, Wv, Wo,
                                           wtq, wtk, wtv, wto);
  }
  {
    dim3 grid(MM / 128, DD / 128, 3);
    gemm_qkv_kernel<<<grid, 256, 0, stream>>>(xb, wtq, wtk, wtv, bq, bk, bv,
                                              Qb, Kb, VTb);
  }
  {
    attn_kernel<<<512, 256, 0, stream>>>(Qb, Kb, VTb, ctx);
  }
  {
    dim3 grid(MM / 128, DD / 128);
    gemm_out_kernel<<<grid, 256, 0, stream>>>(ctx, wto, bo, out);
  }
}

// Round 13
// 224.313 us; speedup vs baseline: 1.0459x; 1.0459x over previous
//
#include <hip/hip_runtime.h>
#include <hip/hip_bf16.h>

typedef unsigned short u16;
typedef __attribute__((ext_vector_type(8))) short bf16x8;
typedef __attribute__((ext_vector_type(4))) short bf16x4;
typedef __attribute__((ext_vector_type(4))) float f32x4;

#define DD 1024
#define TT 2048
#define HH 16
#define BB 4
#define DK 64
#define MM 8192  // B*T

#define QSCALE 0.180336880f  // 0.125 * log2(e)

__device__ __forceinline__ u16 f2b(float x) {
  __hip_bfloat16 h = __float2bfloat16(x);
  return *reinterpret_cast<u16*>(&h);
}

// packed f32x2 -> bf16x2 (v_cvt_pk_bf16_f32)
__device__ __forceinline__ unsigned pk2(float a, float b) {
  float2 t; t.x = a; t.y = b;
  __hip_bfloat162 h = __float22bfloat162_rn(t);
  union { __hip_bfloat162 h; unsigned u; } cv;
  cv.h = h;
  return cv.u;
}

#define GLD16(gp, lp)                                                         \
  __builtin_amdgcn_global_load_lds(                                           \
      (const __attribute__((address_space(1))) unsigned int*)(gp),            \
      (__attribute__((address_space(3))) unsigned int*)(lp), 16, 0, 0)

// ---------------- cast fp32 -> bf16 ----------------
// (separate dispatch: round-12 post-mortem — merging cast+transpose into one
// prep kernel cost ~10us on the non-attn pipeline; reverted)
__global__ __launch_bounds__(256) void cast_bf16_kernel(
    const float* __restrict__ src, u16* __restrict__ dst, int n) {
  int i = (blockIdx.x * 256 + threadIdx.x) * 4;
  if (i + 3 < n) {
    float4 v = *reinterpret_cast<const float4*>(src + i);
    ushort4 o;
    o.x = f2b(v.x); o.y = f2b(v.y); o.z = f2b(v.z); o.w = f2b(v.w);
    *reinterpret_cast<ushort4*>(dst + i) = o;
  }
}

// ---------------- transpose + cast weights: W (K x N) -> Wt (N x K) bf16 ----
__global__ __launch_bounds__(256) void transpose_cast_kernel(
    const float* __restrict__ W0, const float* __restrict__ W1,
    const float* __restrict__ W2, const float* __restrict__ W3,
    u16* __restrict__ O0, u16* __restrict__ O1,
    u16* __restrict__ O2, u16* __restrict__ O3) {
  const float* W; u16* O;
  switch (blockIdx.z) {
    case 0: W = W0; O = O0; break;
    case 1: W = W1; O = O1; break;
    case 2: W = W2; O = O2; break;
    default: W = W3; O = O3; break;
  }
  __shared__ float tile[32][33];
  int tx = threadIdx.x, ty = threadIdx.y;
  int bx = blockIdx.x * 32;
  int by = blockIdx.y * 32;
#pragma unroll
  for (int j = 0; j < 4; j++)
    tile[ty + j * 8][tx] = W[(size_t)(by + ty + j * 8) * DD + bx + tx];
  __syncthreads();
#pragma unroll
  for (int j = 0; j < 4; j++)
    O[(size_t)(bx + ty + j * 8) * DD + by + tx] = f2b(tile[tx][ty + j * 8]);
}

// ============ common 128x128 MFMA GEMM body, BK=64, XOR-swizzled LDS =======
#define GEMM_STAGE(Aptr, Bptr, Asl, Bsl)                                      \
  _Pragma("unroll") for (int c = 0; c < 4; c++) {                             \
    int idx = tid * 8 + c * 2048;                                             \
    int row = idx >> 6, ck = idx & 63;                                        \
    int src = ck ^ ((row & 7) << 3);                                          \
    GLD16(Aptr + (size_t)(m0 + row) * DD + k0 + src, Asl + idx);              \
    GLD16(Bptr + (size_t)(n0 + row) * DD + k0 + src, Bsl + idx);              \
  }

#define GEMM_MFMA(Asl, Bsl)                                                   \
  _Pragma("unroll") for (int half = 0; half < 2; half++) {                    \
    bf16x8 af[4], bfr[4];                                                     \
    _Pragma("unroll") for (int mb = 0; mb < 4; mb++) {                        \
      int r = wm + mb * 16 + l16;                                             \
      af[mb] = *reinterpret_cast<const bf16x8*>(                              \
          &Asl[r * 64 + ((half * 32 + quad * 8) ^ ((r & 7) << 3))]);          \
    }                                                                         \
    _Pragma("unroll") for (int nb = 0; nb < 4; nb++) {                        \
      int r = wn + nb * 16 + l16;                                             \
      bfr[nb] = *reinterpret_cast<const bf16x8*>(                             \
          &Bsl[r * 64 + ((half * 32 + quad * 8) ^ ((r & 7) << 3))]);          \
    }                                                                         \
    _Pragma("unroll") for (int mb = 0; mb < 4; mb++)                          \
      _Pragma("unroll") for (int nb = 0; nb < 4; nb++)                        \
          acc[mb][nb] = __builtin_amdgcn_mfma_f32_16x16x32_bf16(              \
              af[mb], bfr[nb], acc[mb][nb], 0, 0, 0);                         \
  }

// ---------------- fused QKV GEMM: grid (64, 8, 3) ----------------
__global__ __launch_bounds__(256, 4) void gemm_qkv_kernel(
    const u16* __restrict__ A,
    const u16* __restrict__ WtQ, const u16* __restrict__ WtK,
    const u16* __restrict__ WtV,
    const float* __restrict__ bq, const float* __restrict__ bk,
    const float* __restrict__ bv,
    u16* __restrict__ Qo, u16* __restrict__ Ko, u16* __restrict__ Vo) {
  __shared__ __align__(16) u16 smem[17408];  // 34816 B union
  u16* As = smem;          // [128][64] main loop
  u16* Bs = smem + 8192;   // [128][64] main loop
  u16* Vs = smem;          // [128][136] epilogue overlay (z==2 only)
  int z = blockIdx.z;
  const u16* Bt = (z == 0) ? WtQ : ((z == 1) ? WtK : WtV);
  const float* bias = (z == 0) ? bq : ((z == 1) ? bk : bv);
  int tid = threadIdx.x;
  int wave = tid >> 6, lane = tid & 63;
  int quad = lane >> 4, l16 = lane & 15;
  int m0 = blockIdx.x * 128, n0 = blockIdx.y * 128;
  int wm = (wave >> 1) * 64, wn = (wave & 1) * 64;

  f32x4 acc[4][4];
#pragma unroll
  for (int i = 0; i < 4; i++)
#pragma unroll
    for (int j = 0; j < 4; j++) acc[i][j] = (f32x4){0.f, 0.f, 0.f, 0.f};

  for (int k0 = 0; k0 < DD; k0 += 64) {
    GEMM_STAGE(A, Bt, As, Bs)
    __syncthreads();
    GEMM_MFMA(As, Bs)
    __syncthreads();
  }
  // final loop barrier done: As/Bs dead, Vs overlay is safe.

  if (z == 2) {  // V: transpose to (B,H,64,T) via LDS
#pragma unroll
    for (int mb = 0; mb < 4; mb++)
#pragma unroll
      for (int nb = 0; nb < 4; nb++) {
        int col = wn + nb * 16 + l16;
        float bv2 = bias[n0 + col];
#pragma unroll
        for (int r = 0; r < 4; r++) {
          int row = wm + mb * 16 + quad * 4 + r;
          Vs[col * 136 + row] = f2b(acc[mb][nb][r] + bv2);
        }
      }
    __syncthreads();
    int b = m0 >> 11;
    int tloc = m0 & 2047;
#pragma unroll
    for (int i = 0; i < 8; i++) {
      int idx = tid * 8 + i * 2048;
      int row = idx >> 7, col = idx & 127;
      uint4 v = *reinterpret_cast<const uint4*>(&Vs[row * 136 + col]);
      int ncol = n0 + row, h = ncol >> 6, dd = ncol & 63;
      *reinterpret_cast<uint4*>(
          Vo + (((size_t)(b * HH + h) * DK) + dd) * TT + tloc + col) = v;
    }
    return;
  }

  u16* outp = (z == 0) ? Qo : Ko;
  float scale = (z == 0) ? QSCALE : 1.0f;
#pragma unroll
  for (int mb = 0; mb < 4; mb++) {
#pragma unroll
    for (int nb = 0; nb < 4; nb++) {
      int col = n0 + wn + nb * 16 + l16;
      float bv2 = bias[col];
#pragma unroll
      for (int r = 0; r < 4; r++) {
        int row = m0 + wm + mb * 16 + quad * 4 + r;
        float val = (acc[mb][nb][r] + bv2) * scale;
        int hh = col >> 6, dd = col & 63;
        int b = row >> 11, t = row & 2047;
        outp[(((size_t)(b * HH + hh) * TT) + t) * DK + dd] = f2b(val);
      }
    }
  }
}

// ---------------- output-projection GEMM (ctx @ Wo + bo -> fp32) ----------
__global__ __launch_bounds__(256, 4) void gemm_out_kernel(
    const u16* __restrict__ A, const u16* __restrict__ Bt,
    const float* __restrict__ bias, float* __restrict__ outp) {
  __shared__ __align__(16) u16 As[128 * 64];
  __shared__ __align__(16) u16 Bs[128 * 64];
  int tid = threadIdx.x;
  int wave = tid >> 6, lane = tid & 63;
  int quad = lane >> 4, l16 = lane & 15;
  int m0 = blockIdx.x * 128, n0 = blockIdx.y * 128;
  int wm = (wave >> 1) * 64, wn = (wave & 1) * 64;

  f32x4 acc[4][4];
#pragma unroll
  for (int i = 0; i < 4; i++)
#pragma unroll
    for (int j = 0; j < 4; j++) acc[i][j] = (f32x4){0.f, 0.f, 0.f, 0.f};

  for (int k0 = 0; k0 < DD; k0 += 64) {
    GEMM_STAGE(A, Bt, As, Bs)
    __syncthreads();
    GEMM_MFMA(As, Bs)
    __syncthreads();
  }

#pragma unroll
  for (int mb = 0; mb < 4; mb++) {
#pragma unroll
    for (int nb = 0; nb < 4; nb++) {
      int col = n0 + wn + nb * 16 + l16;
      float bv = bias[col];
#pragma unroll
      for (int r = 0; r < 4; r++) {
        int row = m0 + wm + mb * 16 + quad * 4 + r;
        outp[(size_t)row * DD + col] = acc[mb][nb][r] + bv;
      }
    }
  }
}

// ---------------- flash attention: KVBLK=128, 32 q-rows/wave, DMA staging --
// Round-12 attn (phase-split ILP, 60us) + PAIRED K=32 PV/lsum:
// per kt per wave MFMA count 112 -> 72 (QK 32 + lsum 8 + PV 32), and the
// oacc accumulation chain halves (8 -> 4 dependent MFMAs per dt per kt).
// Pairing correctness: kb pair (2j, 2j+1) -> pk8 = {P(2j) | P(2j+1)},
// vf8 = {V(2j) | V(2j+1)} placed at the SAME (quad,reg) slots on the A and
// B side. Our QK usage (kf/qf both at d=quad*8+i) passing refcheck proves
// A-frag and B-frag of mfma_f32_16x16x32_bf16 share one (quad,reg)->k map,
// so any consistent key placement computes sum_k P[k]V[k] exactly.
// Diagonal pair j==wave: s=0 -> hi half = -inf (exp2 -> 0), lo masked;
// s=1 -> lo full, hi masked.
// grid 512 (64 bh x 8 px), block 256 (4 waves). Wave owns 32 q-rows as TWO
// 16-row subblocks (s=0,1) sharing every K/V fragment read.
// Zero-register DMA staging via global_load_lds into unpadded swizzled LDS
// (round-8: register staging spilled). T5 setprio (+3%, round 11).
// Swizzles: K[2][128][64]: src col^((key&7)<<3), read (..)^((l16&7)<<3).
//   V[2][64][128]: 16B granule G=key>>3, src G^(d&7); read granule
//   (4j+{0,2}+(quad>>1))^l8, elem offset (quad&1)*4.
// Paired q-tiles qt=15-px then px: 17 kt per block, no straggler tail.
// launch_bounds (256,2): cap 256 VGPR; watch WRITE_SIZE for spill regression.
__global__ __launch_bounds__(256, 2) void attn_kernel(
    const u16* __restrict__ Q, const u16* __restrict__ K,
    const u16* __restrict__ VT, u16* __restrict__ ctx) {
  __shared__ __align__(16) u16 Ks[2][128][64];   // [buf][key][d]
  __shared__ __align__(16) u16 Vt[2][64][128];   // [buf][d][key]

  int tid = threadIdx.x;
  int wave = tid >> 6, lane = tid & 63;
  int quad = lane >> 4, l16 = lane & 15;
  int bid = blockIdx.x;
  int bh = bid & 63;
  int px = bid >> 6;  // 0..7
  int b = bh >> 4, h = bh & 15;
  const u16* Qh = Q + (size_t)bh * TT * DK;
  const u16* Kh = K + (size_t)bh * TT * DK;
  const u16* Vh = VT + (size_t)bh * DK * TT;

  const bf16x8 ones8 = (bf16x8){0x3F80, 0x3F80, 0x3F80, 0x3F80,
                                0x3F80, 0x3F80, 0x3F80, 0x3F80};  // bf16 1.0
  int l8 = l16 & 7;            // hoisted swizzle masks
  int ksw = l8 << 3;

// stage K/V tile (ktile) into buffer bb via async DMA, zero registers
#define ATTN_STAGE(bb, ktile)                                                 \
  _Pragma("unroll") for (int c = 0; c < 4; c++) {                             \
    int idx = tid * 8 + c * 2048;                                             \
    int krow = idx >> 6, kcol = idx & 63;                                     \
    GLD16(Kh + (size_t)(ktile) * 8192 + krow * 64 +                           \
              (kcol ^ ((krow & 7) << 3)),                                     \
          &Ks[bb][0][0] + idx);                                               \
    int vd = idx >> 7, vg = (idx & 127) >> 3;                                 \
    GLD16(Vh + (size_t)vd * TT + (ktile) * 128 + ((vg ^ (vd & 7)) << 3),      \
          &Vt[bb][0][0] + idx);                                               \
  }

  for (int phase = 0; phase < 2; phase++) {
    int qtc = phase ? px : (15 - px);
    __syncthreads();  // prev-phase epilogue reused Ks[0] as Obuf

    bf16x8 qf[2][2];
#pragma unroll
    for (int s = 0; s < 2; s++) {
      const u16* qrow =
          Qh + (size_t)(qtc * 128 + wave * 32 + s * 16 + l16) * DK + quad * 8;
      qf[s][0] = *reinterpret_cast<const bf16x8*>(qrow);
      qf[s][1] = *reinterpret_cast<const bf16x8*>(qrow + 32);
    }

    ATTN_STAGE(0, 0)
    __syncthreads();  // drains vmcnt -> tile 0 ready

    f32x4 oacc[2][4];
    f32x4 lsum[2];
#pragma unroll
    for (int s = 0; s < 2; s++) {
      lsum[s] = (f32x4){0.f, 0.f, 0.f, 0.f};
#pragma unroll
      for (int dt = 0; dt < 4; dt++) oacc[s][dt] = (f32x4){0.f, 0.f, 0.f, 0.f};
    }

    for (int kt = 0; kt <= qtc; kt++) {
      int cur = kt & 1, nxt = cur ^ 1;
      bool more = kt < qtc;
      bool diag = kt == qtc;
      if (more) {
        ATTN_STAGE(nxt, kt + 1)  // async; lands before end-of-kt barrier
      }

      __builtin_amdgcn_s_setprio(1);  // favor compute over staging waves

      // ---- PHASE 1: all QK^T MFMAs (independent chains) ----
      f32x4 sacc[8][2];
#pragma unroll
      for (int kb = 0; kb < 8; kb++) {
        if (diag && kb > 2 * wave + 1) continue;  // wave-uniform skip
        int krow = kb * 16 + l16;
        bf16x8 kf0 =
            *reinterpret_cast<const bf16x8*>(&Ks[cur][krow][(quad * 8) ^ ksw]);
        bf16x8 kf1 = *reinterpret_cast<const bf16x8*>(
            &Ks[cur][krow][(32 + quad * 8) ^ ksw]);
#pragma unroll
        for (int s = 0; s < 2; s++) {
          f32x4 t = (f32x4){0.f, 0.f, 0.f, 0.f};
          t = __builtin_amdgcn_mfma_f32_16x16x32_bf16(kf0, qf[s][0], t, 0, 0, 0);
          t = __builtin_amdgcn_mfma_f32_16x16x32_bf16(kf1, qf[s][1], t, 0, 0, 0);
          sacc[kb][s] = t;
        }
      }

      // ---- PHASE 2: mask + exp2 + pack -> paired K=32 lsum/PV ----
#pragma unroll
      for (int j = 0; j < 4; j++) {
        if (diag && j > wave) continue;  // wave-uniform pair skip
        bf16x8 vf8[4];
        int gl = ((j * 4 + (quad >> 1)) ^ l8) << 3;       // keys 32j+quad*4
        int gh = ((j * 4 + 2 + (quad >> 1)) ^ l8) << 3;   // keys 32j+16+quad*4
        int off = (quad & 1) * 4;
#pragma unroll
        for (int dt = 0; dt < 4; dt++) {
          union { bf16x4 h[2]; bf16x8 v; } vv;
          vv.h[0] = *reinterpret_cast<const bf16x4*>(
              &Vt[cur][dt * 16 + l16][gl + off]);
          vv.h[1] = *reinterpret_cast<const bf16x4*>(
              &Vt[cur][dt * 16 + l16][gh + off]);
          vf8[dt] = vv.v;
        }
#pragma unroll
        for (int s = 0; s < 2; s++) {
          f32x4 lo = sacc[2 * j][s];
          f32x4 hi = sacc[2 * j + 1][s];
          if (diag && j == wave) {  // diagonal pair: mask
            if (s == 0) {
#pragma unroll
              for (int r = 0; r < 4; r++) {
                if (quad * 4 + r > l16) lo[r] = -__builtin_inff();
                hi[r] = -__builtin_inff();  // kb=2w+1 fully masked for s=0
              }
            } else {
#pragma unroll
              for (int r = 0; r < 4; r++)
                if (quad * 4 + r > l16) hi[r] = -__builtin_inff();
            }
          }
          float p0 = __builtin_amdgcn_exp2f(lo[0]);
          float p1 = __builtin_amdgcn_exp2f(lo[1]);
          float p2 = __builtin_amdgcn_exp2f(lo[2]);
          float p3 = __builtin_amdgcn_exp2f(lo[3]);
          float p4 = __builtin_amdgcn_exp2f(hi[0]);
          float p5 = __builtin_amdgcn_exp2f(hi[1]);
          float p6 = __builtin_amdgcn_exp2f(hi[2]);
          float p7 = __builtin_amdgcn_exp2f(hi[3]);
          union { unsigned u[4]; bf16x8 v; } pk;
          pk.u[0] = pk2(p0, p1);
          pk.u[1] = pk2(p2, p3);
          pk.u[2] = pk2(p4, p5);
          pk.u[3] = pk2(p6, p7);
          lsum[s] = __builtin_amdgcn_mfma_f32_16x16x32_bf16(
              pk.v, ones8, lsum[s], 0, 0, 0);
#pragma unroll
          for (int dt = 0; dt < 4; dt++)
            oacc[s][dt] = __builtin_amdgcn_mfma_f32_16x16x32_bf16(
                pk.v, vf8[dt], oacc[s][dt], 0, 0, 0);
        }
      }
      __builtin_amdgcn_s_setprio(0);

      __syncthreads();  // single barrier per kt (drains DMA into nxt)
    }

    // lsum[s][r] = row-sum for q = quad*4 + r of subblock s -> invert
    f32x4 inv[2];
#pragma unroll
    for (int s = 0; s < 2; s++)
#pragma unroll
      for (int r = 0; r < 4; r++) inv[s][r] = 1.0f / lsum[s][r];

    // stage O through LDS (wave-private rows of flat Obuf over Ks[0])
    u16* Obuf = &Ks[0][0][0];  // 128 rows x stride 64
#pragma unroll
    for (int s = 0; s < 2; s++)
#pragma unroll
      for (int dt = 0; dt < 4; dt++)
#pragma unroll
        for (int r = 0; r < 4; r++)
          Obuf[(wave * 32 + s * 16 + quad * 4 + r) * 64 + dt * 16 + l16] =
              f2b(oacc[s][dt][r] * inv[s][r]);
    asm volatile("s_waitcnt lgkmcnt(0)" ::: "memory");
#pragma unroll
    for (int i = 0; i < 4; i++) {
      int idx = lane * 8 + i * 512;
      int row = idx >> 6, colc = idx & 63;  // row 0..31 local to wave
      uint4 v =
          *reinterpret_cast<const uint4*>(&Obuf[(wave * 32 + row) * 64 + colc]);
      int t = qtc * 128 + wave * 32 + row;
      *reinterpret_cast<uint4*>(
          ctx + ((size_t)(b * TT + t)) * DD + h * DK + colc) = v;
    }
  }
#undef ATTN_STAGE
}

// ---------------- launch ----------------
extern "C" void kernel_launch(void* const* d_in, const int* in_sizes, int n_in,
                              void* d_out, int out_size, void* d_ws, size_t ws_size,
                              hipStream_t stream) {
  const float* x  = (const float*)d_in[0];
  const float* Wq = (const float*)d_in[1];
  const float* bq = (const float*)d_in[2];
  const float* Wk = (const float*)d_in[3];
  const float* bk = (const float*)d_in[4];
  const float* Wv = (const float*)d_in[5];
  const float* bv = (const float*)d_in[6];
  const float* Wo = (const float*)d_in[7];
  const float* bo = (const float*)d_in[8];
  float* out = (float*)d_out;

  char* ws = (char*)d_ws;
  size_t off = 0;
  u16* xb  = (u16*)(ws + off); off += (size_t)MM * DD * 2;
  u16* wtq = (u16*)(ws + off); off += (size_t)DD * DD * 2;
  u16* wtk = (u16*)(ws + off); off += (size_t)DD * DD * 2;
  u16* wtv = (u16*)(ws + off); off += (size_t)DD * DD * 2;
  u16* wto = (u16*)(ws + off); off += (size_t)DD * DD * 2;
  u16* Qb  = (u16*)(ws + off); off += (size_t)MM * DD * 2;
  u16* Kb  = (u16*)(ws + off); off += (size_t)MM * DD * 2;
  u16* VTb = (u16*)(ws + off); off += (size_t)MM * DD * 2;
  u16* ctx = (u16*)(ws + off); off += (size_t)MM * DD * 2;

  {
    int n = MM * DD;
    cast_bf16_kernel<<<n / 1024, 256, 0, stream>>>(x, xb, n);
  }
  {
    dim3 grid(DD / 32, DD / 32, 4);
    dim3 block(32, 8);
    transpose_cast_kernel<<<grid, block, 0, stream>>>(Wq, Wk, Wv, Wo, wtq, wtk, wtv, wto);
  }
  {
    dim3 grid(MM / 128, DD / 128, 3);
    gemm_qkv_kernel<<<grid, 256, 0, stream>>>(xb, wtq, wtk, wtv, bq, bk, bv,
                                              Qb, Kb, VTb);
  }
  {
    attn_kernel<<<512, 256, 0, stream>>>(Qb, Kb, VTb, ctx);
  }
  {
    dim3 grid(MM / 128, DD / 128);
    gemm_out_kernel<<<grid, 256, 0, stream>>>(ctx, wto, bo, out);
  }
}